// Round 1
// baseline (229.234 us; speedup 1.0000x reference)
//
#include <hip/hip_runtime.h>
#include <stdint.h>

typedef unsigned long long u64;
typedef unsigned int u32;

#define T_STEPS 64
#define KDIM 784
#define N1 1024
#define NB 2048
#define N2 10

// ---------------- K0: W2 [10][1024] -> W2T [1024][12] (padded rows) ----------------
__global__ void k_w2t(const float* __restrict__ W2, float* __restrict__ W2T) {
    int j = blockIdx.x * blockDim.x + threadIdx.x;
    if (j >= N1) return;
    float r[12];
#pragma unroll
    for (int i = 0; i < 10; ++i) r[i] = W2[i * N1 + j];
    r[10] = 0.f; r[11] = 0.f;
#pragma unroll
    for (int i = 0; i < 12; ++i) W2T[j * 12 + i] = r[i];
}

// ---------------- K1: c1 = X @ W1^T (fp32), fused LIF-1 -> spike bitmask ----------------
#define BM 64
#define BN 64
#define BK 16

__global__ __launch_bounds__(256) void k_gemm_lif1(
    const float* __restrict__ X, const float* __restrict__ W1,
    u64* __restrict__ bits)
{
    __shared__ __align__(16) float As[BK][BM];
    __shared__ __align__(16) float Bs[BK][BN];

    const int tid = threadIdx.x;
    const int tx = tid & 15;        // n-group
    const int ty = tid >> 4;        // m-group
    const int bm = blockIdx.y * BM;
    const int bn = blockIdx.x * BN;

    const int lrow = tid >> 2;            // 0..63
    const int lk   = (tid & 3) << 2;      // 0,4,8,12

    const float* xa = X  + (size_t)(bm + lrow) * KDIM + lk;
    const float* wa = W1 + (size_t)(bn + lrow) * KDIM + lk;

    float acc[4][4];
#pragma unroll
    for (int r = 0; r < 4; ++r)
#pragma unroll
        for (int c = 0; c < 4; ++c) acc[r][c] = 0.f;

    for (int k0 = 0; k0 < KDIM; k0 += BK) {
        float4 a = *(const float4*)(xa + k0);
        float4 b = *(const float4*)(wa + k0);
        __syncthreads();
        As[lk+0][lrow] = a.x; As[lk+1][lrow] = a.y; As[lk+2][lrow] = a.z; As[lk+3][lrow] = a.w;
        Bs[lk+0][lrow] = b.x; Bs[lk+1][lrow] = b.y; Bs[lk+2][lrow] = b.z; Bs[lk+3][lrow] = b.w;
        __syncthreads();
#pragma unroll
        for (int kk = 0; kk < BK; ++kk) {
            float4 av = *(const float4*)(&As[kk][ty << 2]);
            float4 bv = *(const float4*)(&Bs[kk][tx << 2]);
            acc[0][0] += av.x * bv.x; acc[0][1] += av.x * bv.y; acc[0][2] += av.x * bv.z; acc[0][3] += av.x * bv.w;
            acc[1][0] += av.y * bv.x; acc[1][1] += av.y * bv.y; acc[1][2] += av.y * bv.z; acc[1][3] += av.y * bv.w;
            acc[2][0] += av.z * bv.x; acc[2][1] += av.z * bv.y; acc[2][2] += av.z * bv.z; acc[2][3] += av.z * bv.w;
            acc[3][0] += av.w * bv.x; acc[3][1] += av.w * bv.y; acc[3][2] += av.w * bv.z; acc[3][3] += av.w * bv.w;
        }
    }

    // LIF layer 1: exact per-step recurrence, spikes recorded as 64-bit mask.
    float c[16], v[16];
    u32 blo[16], bhi[16];
#pragma unroll
    for (int u = 0; u < 16; ++u) {
        c[u] = acc[u >> 2][u & 3];
        v[u] = 0.f; blo[u] = 0u; bhi[u] = 0u;
    }
    for (int t = 0; t < 32; ++t) {
#pragma unroll
        for (int u = 0; u < 16; ++u) {
            v[u] += (c[u] - v[u]) * 0.5f;           // v += (c - v)/tau, tau=2
            bool s = v[u] >= 1.0f;                  // spike(v - 1) == (v >= 1)
            blo[u] |= (s ? 1u : 0u) << t;
            v[u] = s ? 0.f : v[u];                  // hard reset
        }
    }
    for (int t = 0; t < 32; ++t) {
#pragma unroll
        for (int u = 0; u < 16; ++u) {
            v[u] += (c[u] - v[u]) * 0.5f;
            bool s = v[u] >= 1.0f;
            bhi[u] |= (s ? 1u : 0u) << t;
            v[u] = s ? 0.f : v[u];
        }
    }
#pragma unroll
    for (int u = 0; u < 16; ++u) {
        int r = u >> 2, cc = u & 3;
        bits[(size_t)(bm + (ty << 2) + r) * N1 + (bn + (tx << 2) + cc)] =
            ((u64)bhi[u] << 32) | (u64)blo[u];
    }
}

// ---------------- K3: c2 from spike bitmasks (lane = timestep), LIF-2, write out ----------------
// block = 256 threads = 4 waves; handles 2 batch elements; each b covered by 2 waves (j halves).
__global__ __launch_bounds__(256) void k_lif2(
    const u64* __restrict__ bits, const float* __restrict__ W2T,
    float* __restrict__ out)
{
    __shared__ float c2s[2][2][64][10];   // [b_sub][j_half][t][i]
    __shared__ float s2s[2][64][10];      // [b_sub][t][i]

    const int tid  = threadIdx.x;
    const int w    = tid >> 6;    // wave 0..3
    const int lane = tid & 63;    // = timestep t
    const int bsub = w >> 1;
    const int jh   = w & 1;
    const int b    = (blockIdx.x << 1) + bsub;

    const u64*   row   = bits + (size_t)b * N1 + jh * 512;
    const float* wbase = W2T + jh * 512 * 12;

    float acc[10];
#pragma unroll
    for (int i = 0; i < 10; ++i) acc[i] = 0.f;

    for (int j = 0; j < 512; j += 2) {
        ulonglong2 bb = *(const ulonglong2*)(row + j);   // wave-uniform load
        if (bb.x) {                                      // uniform skip: ~84% of neurons never spike
            float sf = (float)((bb.x >> lane) & 1ULL);
            const float* wr = wbase + j * 12;
            float4 w0 = *(const float4*)(wr);
            float4 w1 = *(const float4*)(wr + 4);
            float2 w2 = *(const float2*)(wr + 8);
            acc[0] += sf * w0.x; acc[1] += sf * w0.y; acc[2] += sf * w0.z; acc[3] += sf * w0.w;
            acc[4] += sf * w1.x; acc[5] += sf * w1.y; acc[6] += sf * w1.z; acc[7] += sf * w1.w;
            acc[8] += sf * w2.x; acc[9] += sf * w2.y;
        }
        if (bb.y) {
            float sf = (float)((bb.y >> lane) & 1ULL);
            const float* wr = wbase + (j + 1) * 12;
            float4 w0 = *(const float4*)(wr);
            float4 w1 = *(const float4*)(wr + 4);
            float2 w2 = *(const float2*)(wr + 8);
            acc[0] += sf * w0.x; acc[1] += sf * w0.y; acc[2] += sf * w0.z; acc[3] += sf * w0.w;
            acc[4] += sf * w1.x; acc[5] += sf * w1.y; acc[6] += sf * w1.z; acc[7] += sf * w1.w;
            acc[8] += sf * w2.x; acc[9] += sf * w2.y;
        }
    }

#pragma unroll
    for (int i = 0; i < 10; ++i) c2s[bsub][jh][lane][i] = acc[i];
    __syncthreads();

    // LIF layer 2: serial over t, lanes 0..9 of waves 0..1 each own one output channel.
    if (w < 2 && lane < 10) {
        const int i = lane;
        float v2 = 0.f;
        for (int t = 0; t < 64; ++t) {
            float cc = c2s[w][0][t][i] + c2s[w][1][t][i];
            v2 += (cc - v2) * 0.5f;
            bool s = v2 >= 1.0f;
            s2s[w][t][i] = s ? 1.f : 0.f;
            v2 = s ? 0.f : v2;
        }
    }
    __syncthreads();

    // write out[t][b][i], 2 b's * 10 i per t for this block
    const int b0 = blockIdx.x << 1;
    for (int idx = tid; idx < 64 * 20; idx += 256) {
        int t = idx / 20, r = idx % 20;
        out[(size_t)t * (NB * N2) + (size_t)b0 * N2 + r] = s2s[r / 10][t][r % 10];
    }
}

extern "C" void kernel_launch(void* const* d_in, const int* in_sizes, int n_in,
                              void* d_out, int out_size, void* d_ws, size_t ws_size,
                              hipStream_t stream) {
    const float* X  = (const float*)d_in[0];   // [2048, 784]
    const float* W1 = (const float*)d_in[1];   // [1024, 784]
    const float* W2 = (const float*)d_in[2];   // [10, 1024]
    float* out = (float*)d_out;                // [64, 2048, 10]

    u64*   bits = (u64*)d_ws;                               // 2048*1024*8 = 16 MiB
    float* W2T  = (float*)((char*)d_ws + (size_t)NB * N1 * sizeof(u64)); // 48 KiB

    k_w2t<<<dim3((N1 + 255) / 256), dim3(256), 0, stream>>>(W2, W2T);

    dim3 g1(N1 / BN, NB / BM);   // (16, 32)
    k_gemm_lif1<<<g1, dim3(256), 0, stream>>>(X, W1, bits);

    k_lif2<<<dim3(NB / 2), dim3(256), 0, stream>>>(bits, W2T, out);
}

// Round 3
// 166.144 us; speedup vs baseline: 1.3797x; 1.3797x over previous
//
#include <hip/hip_runtime.h>
#include <stdint.h>

typedef unsigned long long u64;
typedef unsigned int u32;

#define T_STEPS 64
#define KDIM 784
#define N1 1024
#define NB 2048
#define N2 10

// ---------------- K0: W2 [10][1024] -> W2T [1024][12] (padded rows) ----------------
__global__ void k_w2t(const float* __restrict__ W2, float* __restrict__ W2T) {
    int j = blockIdx.x * blockDim.x + threadIdx.x;
    if (j >= N1) return;
    float r[12];
#pragma unroll
    for (int i = 0; i < 10; ++i) r[i] = W2[i * N1 + j];
    r[10] = 0.f; r[11] = 0.f;
#pragma unroll
    for (int i = 0; i < 12; ++i) W2T[j * 12 + i] = r[i];
}

// ---------------- K1: c1 = X @ W1^T (fp32), fused LIF-1 -> spike bitmask ----------------
#define BM 64
#define BN 64
#define BK 16

__global__ __launch_bounds__(256) void k_gemm_lif1(
    const float* __restrict__ X, const float* __restrict__ W1,
    u64* __restrict__ bits)
{
    __shared__ __align__(16) float As[BK][BM];
    __shared__ __align__(16) float Bs[BK][BN];

    const int tid = threadIdx.x;
    const int tx = tid & 15;        // n-group
    const int ty = tid >> 4;        // m-group
    const int bm = blockIdx.y * BM;
    const int bn = blockIdx.x * BN;

    const int lrow = tid >> 2;            // 0..63
    const int lk   = (tid & 3) << 2;      // 0,4,8,12

    const float* xa = X  + (size_t)(bm + lrow) * KDIM + lk;
    const float* wa = W1 + (size_t)(bn + lrow) * KDIM + lk;

    float acc[4][4];
#pragma unroll
    for (int r = 0; r < 4; ++r)
#pragma unroll
        for (int c = 0; c < 4; ++c) acc[r][c] = 0.f;

    // register prefetch of first tile
    float4 a = *(const float4*)(xa);
    float4 b = *(const float4*)(wa);

    for (int k0 = 0; k0 < KDIM; k0 += BK) {
        __syncthreads();
        As[lk+0][lrow] = a.x; As[lk+1][lrow] = a.y; As[lk+2][lrow] = a.z; As[lk+3][lrow] = a.w;
        Bs[lk+0][lrow] = b.x; Bs[lk+1][lrow] = b.y; Bs[lk+2][lrow] = b.z; Bs[lk+3][lrow] = b.w;
        __syncthreads();
        if (k0 + BK < KDIM) {       // prefetch next tile; latency hides under FMAs below
            a = *(const float4*)(xa + k0 + BK);
            b = *(const float4*)(wa + k0 + BK);
        }
#pragma unroll
        for (int kk = 0; kk < BK; ++kk) {
            float4 av = *(const float4*)(&As[kk][ty << 2]);
            float4 bv = *(const float4*)(&Bs[kk][tx << 2]);
            acc[0][0] += av.x * bv.x; acc[0][1] += av.x * bv.y; acc[0][2] += av.x * bv.z; acc[0][3] += av.x * bv.w;
            acc[1][0] += av.y * bv.x; acc[1][1] += av.y * bv.y; acc[1][2] += av.y * bv.z; acc[1][3] += av.y * bv.w;
            acc[2][0] += av.z * bv.x; acc[2][1] += av.z * bv.y; acc[2][2] += av.z * bv.z; acc[2][3] += av.z * bv.w;
            acc[3][0] += av.w * bv.x; acc[3][1] += av.w * bv.y; acc[3][2] += av.w * bv.z; acc[3][3] += av.w * bv.w;
        }
    }

    // LIF layer 1: exact per-step recurrence, spikes recorded as 64-bit mask.
    float c[16], v[16];
    u32 blo[16], bhi[16];
#pragma unroll
    for (int u = 0; u < 16; ++u) {
        c[u] = acc[u >> 2][u & 3];
        v[u] = 0.f; blo[u] = 0u; bhi[u] = 0u;
    }
    for (int t = 0; t < 32; ++t) {
#pragma unroll
        for (int u = 0; u < 16; ++u) {
            v[u] += (c[u] - v[u]) * 0.5f;           // v += (c - v)/tau, tau=2
            bool s = v[u] >= 1.0f;                  // spike(v - 1) == (v >= 1)
            blo[u] |= (s ? 1u : 0u) << t;
            v[u] = s ? 0.f : v[u];                  // hard reset
        }
    }
    for (int t = 0; t < 32; ++t) {
#pragma unroll
        for (int u = 0; u < 16; ++u) {
            v[u] += (c[u] - v[u]) * 0.5f;
            bool s = v[u] >= 1.0f;
            bhi[u] |= (s ? 1u : 0u) << t;
            v[u] = s ? 0.f : v[u];
        }
    }
#pragma unroll
    for (int u = 0; u < 16; ++u) {
        int r = u >> 2, cc = u & 3;
        bits[(size_t)(bm + (ty << 2) + r) * N1 + (bn + (tx << 2) + cc)] =
            ((u64)bhi[u] << 32) | (u64)blo[u];
    }
}

// ---------------- K3: sparse c2 via compaction, LIF-2, write out ----------------
// 1 wave = 1 batch element; block = 4 waves = 4 consecutive batches.
// Phase 1: lane-parallel scan of 1024 bitmasks, ballot-compact active ones into LDS.
// Phase 2: dense loop over ~16% active neurons; lane = timestep, 10 FMAs each.
__global__ __launch_bounds__(256) void k_lif2(
    const u64* __restrict__ bits, const float* __restrict__ W2T,
    float* __restrict__ out)
{
    __shared__ u64  masksS[4][N1];      // 32 KB
    __shared__ u32  idxS[4][N1];        // 16 KB
    __shared__ float c2S[4][64][12];    // 12 KB
    __shared__ float s2S[4][64][10];    // 10 KB   (total 70 KB -> 2 blocks/CU)

    const int tid  = threadIdx.x;
    const int w    = tid >> 6;      // wave = batch sub-index
    const int lane = tid & 63;
    const int b    = (blockIdx.x << 2) + w;

    const u64* row = bits + (size_t)b * N1;

    // ---- phase 1: scan + compact (coalesced, lane-parallel) ----
    int nact = 0;
#pragma unroll
    for (int it = 0; it < 16; ++it) {
        u64 m = row[lane + (it << 6)];
        u64 ball = __ballot(m != 0ULL);
        int pos = nact + __popcll(ball & ((1ULL << lane) - 1ULL));
        if (m != 0ULL) { masksS[w][pos] = m; idxS[w][pos] = lane + (it << 6); }
        nact += __popcll(ball);
    }

    // ---- phase 2: dense accumulation over active neurons; lane = t ----
    float acc[10];
#pragma unroll
    for (int i = 0; i < 10; ++i) acc[i] = 0.f;

#define LIF2_BODY(A)                                                      \
    {                                                                     \
        u64 m = masksS[w][(A)];                                           \
        int j = __builtin_amdgcn_readfirstlane((int)idxS[w][(A)]);        \
        float sf = (float)((m >> lane) & 1ULL);                           \
        const float* wr = W2T + j * 12;                                   \
        float4 w0 = *(const float4*)(wr);                                 \
        float4 w1 = *(const float4*)(wr + 4);                             \
        float2 w2 = *(const float2*)(wr + 8);                             \
        acc[0] += sf * w0.x; acc[1] += sf * w0.y;                         \
        acc[2] += sf * w0.z; acc[3] += sf * w0.w;                         \
        acc[4] += sf * w1.x; acc[5] += sf * w1.y;                         \
        acc[6] += sf * w1.z; acc[7] += sf * w1.w;                         \
        acc[8] += sf * w2.x; acc[9] += sf * w2.y;                         \
    }

    int a = 0;
    for (; a + 2 <= nact; a += 2) { LIF2_BODY(a); LIF2_BODY(a + 1); }
    if (a < nact) LIF2_BODY(a);
#undef LIF2_BODY

#pragma unroll
    for (int i = 0; i < 10; ++i) c2S[w][lane][i] = acc[i];
    __syncthreads();

    // ---- LIF layer 2: serial over t; 40 threads (4 batches x 10 channels) ----
    if (tid < 40) {
        const int w2 = tid / 10, i = tid % 10;
        float v2 = 0.f;
        for (int t = 0; t < 64; ++t) {
            float cc = c2S[w2][t][i];
            v2 += (cc - v2) * 0.5f;
            bool s = v2 >= 1.0f;
            s2S[w2][t][i] = s ? 1.f : 0.f;
            v2 = s ? 0.f : v2;
        }
    }
    __syncthreads();

    // ---- write out[t][b0..b0+3][0..9]: contiguous 160B per t ----
    const int b0 = blockIdx.x << 2;
    for (int idx = tid; idx < 64 * 40; idx += 256) {
        int t = idx / 40, r = idx % 40;
        out[(size_t)t * (NB * N2) + (size_t)b0 * N2 + r] = s2S[r / 10][t][r % 10];
    }
}

extern "C" void kernel_launch(void* const* d_in, const int* in_sizes, int n_in,
                              void* d_out, int out_size, void* d_ws, size_t ws_size,
                              hipStream_t stream) {
    const float* X  = (const float*)d_in[0];   // [2048, 784]
    const float* W1 = (const float*)d_in[1];   // [1024, 784]
    const float* W2 = (const float*)d_in[2];   // [10, 1024]
    float* out = (float*)d_out;                // [64, 2048, 10]

    u64*   bits = (u64*)d_ws;                               // 16 MiB
    float* W2T  = (float*)((char*)d_ws + (size_t)NB * N1 * sizeof(u64)); // 48 KiB

    k_w2t<<<dim3((N1 + 255) / 256), dim3(256), 0, stream>>>(W2, W2T);

    dim3 g1(N1 / BN, NB / BM);   // (16, 32)
    k_gemm_lif1<<<g1, dim3(256), 0, stream>>>(X, W1, bits);

    k_lif2<<<dim3(NB / 4), dim3(256), 0, stream>>>(bits, W2T, out);
}